// Round 1
// baseline (22312.697 us; speedup 1.0000x reference)
//
#include <hip/hip_runtime.h>
#include <hip/hip_bf16.h>
#include <math.h>

// ---------------- constants ----------------
#define PI_F 3.14159265358979323846f
#define TWO_PI_F 6.283185307179586f

constexpr int BB = 4;            // batch
constexpr int FF_ = 2048;        // frames
constexpr int RC = 512;          // rnn channels
constexpr int HOP = 256;
constexpr int KK = 1024;         // FIR len
constexpr int LL = HOP + KK - 1; // 1279
constexpr size_t TOT = 525311;   // (F-1)*HOP + L
constexpr int APAD = 24064;      // zero pad in front of audio rows (>= REV-1, mult of 64)
constexpr size_t AROW = 549376;  // APAD + 525312
constexpr int REV = 24000;

// output offsets (floats)
constexpr size_t O1 = 2101244;   // oq
constexpr size_t O2 = 2109436;   // v_gain
constexpr size_t O3 = 2117628;   // u_gain
constexpr size_t O4 = 2125820;   // ff
constexpr size_t O5 = 2158588;   // fb

// workspace offsets (bytes)
constexpr size_t OFF_X      = 0;                 // 8192*512*4
constexpr size_t OFF_GI     = 16777216;          // 8192*1536*4
constexpr size_t OFF_HS     = 67108864;          // 8192*512*4
constexpr size_t OFF_FILTR  = 0;                 // 8192*1024*4 (overlays X/GI, dead by then)
constexpr size_t OFF_OQ     = 83886080;
constexpr size_t OFF_VG     = 83918848;
constexpr size_t OFF_UG     = 83951616;
constexpr size_t OFF_FFW    = 83984384;
constexpr size_t OFF_FBW    = 84115456;
constexpr size_t OFF_START  = 84246528;
constexpr size_t OFF_F0M    = 84279296;
constexpr size_t OFF_BAR    = 84279552;          // cnt @+0, gen @+128
constexpr size_t OFF_HBUF   = 84279808;          // 2*2048 floats
constexpr size_t OFF_EXC    = 84296192;          // 8192*256*4
constexpr size_t OFF_AUDIO  = 92684800;          // 4*549376*4

__device__ __forceinline__ float softplusf(float x) {
  return x > 20.0f ? x : log1pf(expf(x));
}
__device__ __forceinline__ float sigmoidf_(float x) {
  return 1.0f / (1.0f + expf(-x));
}

// ---------------- f0 mean per batch ----------------
__global__ __launch_bounds__(256) void k_f0mean(const float* __restrict__ f0, float* __restrict__ f0m) {
  int b = blockIdx.x, tid = threadIdx.x;
  float s = 0.f;
  for (int t = tid; t < FF_; t += 256) s += f0[b*FF_ + t];
  #pragma unroll
  for (int m = 1; m < 64; m <<= 1) s += __shfl_xor(s, m);
  __shared__ float ws4[4];
  if ((tid & 63) == 0) ws4[tid >> 6] = s;
  __syncthreads();
  if (tid == 0) f0m[b] = (ws4[0] + ws4[1] + ws4[2] + ws4[3]) * (1.0f / 2048.0f);
}

// ---------------- input projection: x = relu(concat @ W_in^T + b_in) ----------------
__global__ __launch_bounds__(256) void k_inproj(
    const float* __restrict__ f0, const float* __restrict__ loud,
    const float* __restrict__ gender, const float* __restrict__ age,
    const float* __restrict__ z, const float* __restrict__ f0m,
    const float* __restrict__ Win, const float* __restrict__ bin,
    float* __restrict__ x)
{
  __shared__ float inp[16 * 28];
  int r0 = blockIdx.x * 16;   // bf base
  int tid = threadIdx.x;
  for (int i = tid; i < 16 * 28; i += 256) {
    int r = i / 28, c = i % 28;
    int bf = r0 + r, b = bf >> 11;
    float v;
    if (c == 0)       v = f0[bf] - f0m[b];
    else if (c == 1)  v = loud[bf];
    else if (c < 4)   v = gender[(size_t)bf*2 + (c - 2)];
    else if (c < 12)  v = age[(size_t)bf*8 + (c - 4)];
    else              v = z[(size_t)bf*16 + (c - 12)];
    inp[i] = v;
  }
  __syncthreads();
  for (int o = tid; o < 16 * 512; o += 256) {
    int r = o >> 9, j = o & 511;
    const float* w = Win + j * 28;
    const float* ip = inp + r * 28;
    float a = bin[j];
    #pragma unroll
    for (int c2 = 0; c2 < 28; ++c2) a = fmaf(w[c2], ip[c2], a);
    x[(size_t)(r0 + r) * 512 + j] = fmaxf(a, 0.0f);
  }
}

// ---------------- GEMM: gi = x @ W_ih^T + b_ih  (M=8192, N=1536, K=512) ----------------
__global__ __launch_bounds__(256) void k_gemm_gi(
    const float* __restrict__ A, const float* __restrict__ Bw,
    const float* __restrict__ bias, float* __restrict__ C)
{
  __shared__ float As[32 * 68];
  __shared__ float Bs[32 * 68];
  int tid = threadIdx.x;
  int n0 = blockIdx.x * 64, m0 = blockIdx.y * 64;
  int tx = tid & 15, ty = tid >> 4;
  float c[4][4] = {{0.f}};
  for (int k0 = 0; k0 < 512; k0 += 32) {
    __syncthreads();
    for (int i = tid; i < 2048; i += 256) {
      int mm = i >> 5, kk = i & 31;
      As[kk * 68 + mm] = A[(size_t)(m0 + mm) * 512 + k0 + kk];
      Bs[kk * 68 + mm] = Bw[(size_t)(n0 + mm) * 512 + k0 + kk];
    }
    __syncthreads();
    #pragma unroll
    for (int kk = 0; kk < 32; ++kk) {
      float4 a = *(const float4*)&As[kk * 68 + ty * 4];
      float4 b = *(const float4*)&Bs[kk * 68 + tx * 4];
      c[0][0] = fmaf(a.x, b.x, c[0][0]); c[0][1] = fmaf(a.x, b.y, c[0][1]);
      c[0][2] = fmaf(a.x, b.z, c[0][2]); c[0][3] = fmaf(a.x, b.w, c[0][3]);
      c[1][0] = fmaf(a.y, b.x, c[1][0]); c[1][1] = fmaf(a.y, b.y, c[1][1]);
      c[1][2] = fmaf(a.y, b.z, c[1][2]); c[1][3] = fmaf(a.y, b.w, c[1][3]);
      c[2][0] = fmaf(a.z, b.x, c[2][0]); c[2][1] = fmaf(a.z, b.y, c[2][1]);
      c[2][2] = fmaf(a.z, b.z, c[2][2]); c[2][3] = fmaf(a.z, b.w, c[2][3]);
      c[3][0] = fmaf(a.w, b.x, c[3][0]); c[3][1] = fmaf(a.w, b.y, c[3][1]);
      c[3][2] = fmaf(a.w, b.z, c[3][2]); c[3][3] = fmaf(a.w, b.w, c[3][3]);
    }
  }
  int n = n0 + tx * 4;
  float4 bb = *(const float4*)&bias[n];
  #pragma unroll
  for (int mi = 0; mi < 4; ++mi) {
    int m = m0 + ty * 4 + mi;
    float4 v;
    v.x = c[mi][0] + bb.x; v.y = c[mi][1] + bb.y;
    v.z = c[mi][2] + bb.z; v.w = c[mi][3] + bb.w;
    *(float4*)&C[(size_t)m * 1536 + n] = v;
  }
}

// ---------------- persistent GRU: 64 WGs, 8 hidden units each ----------------
__global__ __launch_bounds__(256) void k_gru(
    const float* __restrict__ Whh, const float* __restrict__ bhh,
    const float* __restrict__ gi, float* __restrict__ hs,
    float* hbuf, unsigned* bar_cnt, unsigned* bar_gen)
{
  __shared__ float wlds[24 * 512];  // 3 gates x 8 units rows of W_hh
  __shared__ float hlds[4 * 514];   // full h, padded
  __shared__ float red[96 * 18];
  __shared__ float ghl[96];
  __shared__ float bhh_s[24];

  const int tid = threadIdx.x;
  const int u0 = blockIdx.x * 8;

  for (int i = tid; i < 24 * 512; i += 256) {
    int row = i >> 9, k = i & 511;
    int g = row >> 3, u = row & 7;
    wlds[i] = Whh[(size_t)(g * 512 + u0 + u) * 512 + k];
  }
  if (tid < 24) {
    int g = tid >> 3, u = tid & 7;
    bhh_s[tid] = bhh[g * 512 + u0 + u];
  }
  const int rg = tid >> 5;   // row group (active < 6)
  const int kc = tid & 31;
  const int uu = tid >> 2;   // update-unit (tid<32)
  const int ub = tid & 3;    // update-batch

  #pragma unroll 1
  for (unsigned t = 0; t < 2048; ++t) {
    const int par = (int)(t & 1u);
    // stage full h (coherent, agent scope)
    #pragma unroll
    for (int it = 0; it < 8; ++it) {
      int i = tid + (it << 8);
      float v = __hip_atomic_load(&hbuf[par * 2048 + i], __ATOMIC_RELAXED, __HIP_MEMORY_SCOPE_AGENT);
      hlds[(i >> 9) * 514 + (i & 511)] = v;
    }
    // prefetch gi for this step
    float gir = 0.f, giz = 0.f, gin = 0.f;
    if (tid < 32) {
      const float* gp = gi + (size_t)(ub * 2048 + (int)t) * 1536 + u0 + uu;
      gir = gp[0]; giz = gp[512]; gin = gp[1024];
    }
    __syncthreads();
    // partial dot products: 24 rows x 4 batches, k split over 32 lanes (interleaved pairs)
    if (rg < 6) {
      float acc[4][4];
      #pragma unroll
      for (int j = 0; j < 4; ++j)
        #pragma unroll
        for (int b2 = 0; b2 < 4; ++b2) acc[j][b2] = 0.f;
      #pragma unroll
      for (int kk = 0; kk < 8; ++kk) {
        int k0 = (kc << 1) + (kk << 6);
        float2 h0 = *(const float2*)&hlds[0 * 514 + k0];
        float2 h1 = *(const float2*)&hlds[1 * 514 + k0];
        float2 h2 = *(const float2*)&hlds[2 * 514 + k0];
        float2 h3 = *(const float2*)&hlds[3 * 514 + k0];
        #pragma unroll
        for (int j = 0; j < 4; ++j) {
          float2 w = *(const float2*)&wlds[(rg * 4 + j) * 512 + k0];
          acc[j][0] = fmaf(w.x, h0.x, fmaf(w.y, h0.y, acc[j][0]));
          acc[j][1] = fmaf(w.x, h1.x, fmaf(w.y, h1.y, acc[j][1]));
          acc[j][2] = fmaf(w.x, h2.x, fmaf(w.y, h2.y, acc[j][2]));
          acc[j][3] = fmaf(w.x, h3.x, fmaf(w.y, h3.y, acc[j][3]));
        }
      }
      #pragma unroll
      for (int j = 0; j < 4; ++j)
        #pragma unroll
        for (int b2 = 0; b2 < 4; ++b2) {
          float v = acc[j][b2];
          v += __shfl_xor(v, 16);
          if (kc < 16) red[((rg * 4 + j) * 4 + b2) * 18 + kc] = v;
        }
    }
    __syncthreads();
    if (tid < 96) {
      float s = 0.f;
      #pragma unroll
      for (int i2 = 0; i2 < 16; i2 += 2) {
        float2 v = *(const float2*)&red[tid * 18 + i2];
        s += v.x + v.y;
      }
      ghl[tid] = s;
    }
    __syncthreads();
    // GRU cell update for owned units
    if (tid < 32) {
      float ghr = ghl[(uu) * 4 + ub]      + bhh_s[uu];
      float ghz = ghl[(8 + uu) * 4 + ub]  + bhh_s[8 + uu];
      float ghn = ghl[(16 + uu) * 4 + ub] + bhh_s[16 + uu];
      float r = sigmoidf_(gir + ghr);
      float zg = sigmoidf_(giz + ghz);
      float n = tanhf(gin + r * ghn);
      float hold = hlds[ub * 514 + u0 + uu];
      float hnew = (1.0f - zg) * n + zg * hold;
      hs[(size_t)(ub * 2048 + (int)t) * 512 + u0 + uu] = hnew;
      __hip_atomic_store(&hbuf[(par ^ 1) * 2048 + ub * 512 + u0 + uu], hnew,
                         __ATOMIC_RELAXED, __HIP_MEMORY_SCOPE_AGENT);
    }
    __syncthreads();
    // device-scope barrier over 64 WGs, monotone generation counter
    if (tid == 0) {
      __threadfence();
      unsigned prev = __hip_atomic_fetch_add(bar_cnt, 1u, __ATOMIC_ACQ_REL, __HIP_MEMORY_SCOPE_AGENT);
      if (prev == 63u) {
        __hip_atomic_store(bar_cnt, 0u, __ATOMIC_RELAXED, __HIP_MEMORY_SCOPE_AGENT);
        __hip_atomic_store(bar_gen, t + 1u, __ATOMIC_RELEASE, __HIP_MEMORY_SCOPE_AGENT);
      } else {
        while (__hip_atomic_load(bar_gen, __ATOMIC_ACQUIRE, __HIP_MEMORY_SCOPE_AGENT) < t + 1u)
          __builtin_amdgcn_s_sleep(2);
      }
      __threadfence();
    }
    __syncthreads();
  }
}

// ---------------- heads: oq, v_gain, u_gain, ff(cumsum), fb ----------------
__global__ __launch_bounds__(256) void k_heads(
    const float* __restrict__ hs,
    const float* __restrict__ Woq, const float* __restrict__ boq,
    const float* __restrict__ Wvg, const float* __restrict__ bvg,
    const float* __restrict__ Wug, const float* __restrict__ bug,
    const float* __restrict__ Wff, const float* __restrict__ bff,
    const float* __restrict__ Wfb, const float* __restrict__ bfb,
    float* __restrict__ out,
    float* __restrict__ oqw, float* __restrict__ vgw, float* __restrict__ ugw,
    float* __restrict__ ffw, float* __restrict__ fbw)
{
  int bf = blockIdx.x, tid = threadIdx.x;
  const float* h = hs + (size_t)bf * 512;
  float p[11];
  #pragma unroll
  for (int i = 0; i < 11; ++i) p[i] = 0.f;
  for (int k = tid; k < 512; k += 256) {
    float hv = h[k];
    p[0] = fmaf(Woq[k], hv, p[0]);
    p[1] = fmaf(Wvg[k], hv, p[1]);
    p[2] = fmaf(Wug[k], hv, p[2]);
    p[3] = fmaf(Wff[k], hv, p[3]);
    p[4] = fmaf(Wff[512 + k], hv, p[4]);
    p[5] = fmaf(Wff[1024 + k], hv, p[5]);
    p[6] = fmaf(Wff[1536 + k], hv, p[6]);
    p[7] = fmaf(Wfb[k], hv, p[7]);
    p[8] = fmaf(Wfb[512 + k], hv, p[8]);
    p[9] = fmaf(Wfb[1024 + k], hv, p[9]);
    p[10] = fmaf(Wfb[1536 + k], hv, p[10]);
  }
  #pragma unroll
  for (int i = 0; i < 11; ++i) {
    float v = p[i];
    #pragma unroll
    for (int m = 1; m < 64; m <<= 1) v += __shfl_xor(v, m);
    p[i] = v;
  }
  __shared__ float r4[4][11];
  if ((tid & 63) == 0) {
    int w = tid >> 6;
    #pragma unroll
    for (int i = 0; i < 11; ++i) r4[w][i] = p[i];
  }
  __syncthreads();
  if (tid == 0) {
    float s[11];
    #pragma unroll
    for (int i = 0; i < 11; ++i) s[i] = r4[0][i] + r4[1][i] + r4[2][i] + r4[3][i];
    float oqv = sigmoidf_(s[0] + boq[0]);
    float vg = softplusf(s[1] + bvg[0]);
    float ug = softplusf(s[2] + bug[0]);
    out[O1 + bf] = oqv; oqw[bf] = oqv;
    out[O2 + bf] = vg;  vgw[bf] = vg;
    out[O3 + bf] = ug;  ugw[bf] = ug;
    float run = 200.0f;
    #pragma unroll
    for (int j = 0; j < 4; ++j) {
      run += softplusf(s[3 + j] + bff[j]);
      out[O4 + (size_t)bf * 4 + j] = run; ffw[(size_t)bf * 4 + j] = run;
    }
    #pragma unroll
    for (int j = 0; j < 4; ++j) {
      float g = softplusf(s[7 + j] + bfb[j]) + 50.0f;
      out[O5 + (size_t)bf * 4 + j] = g; fbw[(size_t)bf * 4 + j] = g;
    }
  }
}

// ---------------- per-batch prefix scan of cycles -> start phase ----------------
__global__ __launch_bounds__(256) void k_scan(const float* __restrict__ f0, float* __restrict__ startw) {
  __shared__ float ts[256];
  int b = blockIdx.x, tid = threadIdx.x;
  const float CY = 256.0f / 24000.0f;
  float c[8], run = 0.f;
  int base = b * 2048 + tid * 8;
  #pragma unroll
  for (int j = 0; j < 8; ++j) { c[j] = run; run += f0[base + j] * CY; }
  ts[tid] = run;
  __syncthreads();
  for (int off = 1; off < 256; off <<= 1) {
    float v = (tid >= off) ? ts[tid - off] : 0.0f;
    __syncthreads();
    ts[tid] += v;
    __syncthreads();
  }
  float excl = (tid == 0) ? 0.0f : ts[tid - 1];
  #pragma unroll
  for (int j = 0; j < 8; ++j) {
    float st = excl + c[j];
    startw[base + j] = st - floorf(st);
  }
}

// ---------------- glottal source + excitation ----------------
__global__ __launch_bounds__(256) void k_excite(
    const float* __restrict__ f0, const float* __restrict__ noise,
    const float* __restrict__ startw, const float* __restrict__ oqw,
    const float* __restrict__ vgw, const float* __restrict__ ugw,
    float* __restrict__ exc)
{
  int bf = blockIdx.x, i = threadIdx.x;
  float st = startw[bf], f0v = f0[bf], oqv = oqw[bf], vg = vgw[bf], ug = ugw[bf];
  float total = st + f0v * ((float)i * (1.0f / 24000.0f));
  float phi = total - floorf(total);
  float peak = oqv * 0.66f;
  float rise = 0.5f * (1.0f - cosf(PI_F * phi / (peak + 1e-6f)));
  float fall = cosf(PI_F * (phi - peak) / (2.0f * (oqv - peak) + 1e-6f));
  float v = (phi < peak) ? rise : ((phi < oqv) ? fall : 0.0f);
  exc[(size_t)bf * 256 + i] = v * vg + noise[(size_t)bf * 256 + i] * ug;
}

// ---------------- formant IR generation + normalization (stored reversed) ----------------
__global__ __launch_bounds__(256) void k_ir(
    const float* __restrict__ ffw, const float* __restrict__ fbw,
    float* __restrict__ filtR)
{
  __shared__ float ffs[4], fbs[4], ssc[1], wmax[4];
  int bf = blockIdx.x, tid = threadIdx.x;
  if (tid < 4) { ffs[tid] = ffw[(size_t)bf * 4 + tid]; fbs[tid] = fbw[(size_t)bf * 4 + tid]; }
  __syncthreads();
  float vals[4];
  float am = 0.f;
  #pragma unroll
  for (int it = 0; it < 4; ++it) {
    int k = it * 256 + tid;
    float t = (float)k * (1.0f / 24000.0f);
    float s = 0.f;
    #pragma unroll
    for (int j = 0; j < 4; ++j)
      s += expf(-PI_F * fbs[j] * t) * sinf(TWO_PI_F * ffs[j] * t);
    vals[it] = s;
    am = fmaxf(am, fabsf(s));
  }
  #pragma unroll
  for (int m = 1; m < 64; m <<= 1) am = fmaxf(am, __shfl_xor(am, m));
  if ((tid & 63) == 0) wmax[tid >> 6] = am;
  __syncthreads();
  if (tid == 0) ssc[0] = fmaxf(fmaxf(wmax[0], wmax[1]), fmaxf(wmax[2], wmax[3])) + 1e-8f;
  __syncthreads();
  float inv = 1.0f / ssc[0];
  #pragma unroll
  for (int it = 0; it < 4; ++it) {
    int k = it * 256 + tid;
    filtR[(size_t)bf * 1024 + (1023 - k)] = vals[it] * inv;
  }
}

// ---------------- per-frame FIR conv (full) + overlap-add via atomics ----------------
__global__ __launch_bounds__(256) void k_conv(
    const float* __restrict__ exc, const float* __restrict__ filtR,
    float* __restrict__ audio)
{
  __shared__ float es[256];
  __shared__ float fp[1536];
  int bf = blockIdx.x, tid = threadIdx.x;
  int b = bf >> 11, f = bf & 2047;
  es[tid] = exc[(size_t)bf * 256 + tid];
  for (int i = tid; i < 1536; i += 256) {
    int j = i - 256;
    fp[i] = (j >= 0 && j < 1024) ? filtR[(size_t)bf * 1024 + j] : 0.0f;
  }
  __syncthreads();
  int n0 = tid * 5;
  float V0 = fp[n0 + 256], V1 = fp[n0 + 257], V2 = fp[n0 + 258], V3 = fp[n0 + 259], V4 = fp[n0 + 260];
  float a0 = 0.f, a1 = 0.f, a2 = 0.f, a3 = 0.f, a4 = 0.f;
  #pragma unroll 4
  for (int m = 0; m < 256; ++m) {
    float e = es[m];
    a0 = fmaf(e, V0, a0); a1 = fmaf(e, V1, a1); a2 = fmaf(e, V2, a2);
    a3 = fmaf(e, V3, a3); a4 = fmaf(e, V4, a4);
    V4 = V3; V3 = V2; V2 = V1; V1 = V0;
    V0 = fp[n0 + 255 - m];
  }
  float* arow = audio + (size_t)b * AROW + APAD + (size_t)f * 256;
  if (n0 + 0 < LL) atomicAdd(&arow[n0 + 0], a0);
  if (n0 + 1 < LL) atomicAdd(&arow[n0 + 1], a1);
  if (n0 + 2 < LL) atomicAdd(&arow[n0 + 2], a2);
  if (n0 + 3 < LL) atomicAdd(&arow[n0 + 3], a3);
  if (n0 + 4 < LL) atomicAdd(&arow[n0 + 4], a4);
}

// ---------------- reverb FIR (24000 taps) + wet/dry mix ----------------
__global__ __launch_bounds__(256) void k_reverb(
    const float* __restrict__ audio, const float* __restrict__ ir,
    const float* __restrict__ wetl, float* __restrict__ out)
{
  __shared__ float as_[2376];   // 2304 window + swizzle pad
  __shared__ float irs[256];
  int tb = blockIdx.x, b = blockIdx.y, tid = threadIdx.x;
  int tbase = tb * 2048;
  const float* arow = audio + (size_t)b * AROW;
  float acc[8];
  #pragma unroll
  for (int j = 0; j < 8; ++j) acc[j] = 0.f;

  for (int c = 0; c < 94; ++c) {
    __syncthreads();
    int r = c * 256 + tid;
    irs[tid] = (r < REV) ? ir[r] : 0.0f;
    int B0 = APAD + tbase - c * 256 - 256;   // >= 0 always
    for (int i = tid; i < 2304; i += 256) {
      int g = B0 + i;
      float v = (g < (int)AROW) ? arow[g] : 0.0f;
      as_[i + (i >> 5)] = v;
    }
    __syncthreads();
    int base = 8 * tid + 256;
    int li;
    li = base + 0; float V0 = as_[li + (li >> 5)];
    li = base + 1; float V1 = as_[li + (li >> 5)];
    li = base + 2; float V2 = as_[li + (li >> 5)];
    li = base + 3; float V3 = as_[li + (li >> 5)];
    li = base + 4; float V4 = as_[li + (li >> 5)];
    li = base + 5; float V5 = as_[li + (li >> 5)];
    li = base + 6; float V6 = as_[li + (li >> 5)];
    li = base + 7; float V7 = as_[li + (li >> 5)];
    #pragma unroll 8
    for (int rr = 0; rr < 256; ++rr) {
      float w = irs[rr];
      acc[0] = fmaf(w, V0, acc[0]); acc[1] = fmaf(w, V1, acc[1]);
      acc[2] = fmaf(w, V2, acc[2]); acc[3] = fmaf(w, V3, acc[3]);
      acc[4] = fmaf(w, V4, acc[4]); acc[5] = fmaf(w, V5, acc[5]);
      acc[6] = fmaf(w, V6, acc[6]); acc[7] = fmaf(w, V7, acc[7]);
      V7 = V6; V6 = V5; V5 = V4; V4 = V3; V3 = V2; V2 = V1; V1 = V0;
      int ln = base - 1 - rr;
      V0 = as_[ln + (ln >> 5)];
    }
  }
  float wet = sigmoidf_(wetl[0]);
  #pragma unroll
  for (int j = 0; j < 8; ++j) {
    long t = (long)tbase + 8 * tid + j;
    if (t < (long)TOT) {
      float av = arow[APAD + t];
      out[(size_t)b * TOT + t] = (1.0f - wet) * av + wet * acc[j];
    }
  }
}

// ---------------- launch ----------------
extern "C" void kernel_launch(void* const* d_in, const int* in_sizes, int n_in,
                              void* d_out, int out_size, void* d_ws, size_t ws_size,
                              hipStream_t stream) {
  const float* f0       = (const float*)d_in[0];
  const float* loud     = (const float*)d_in[1];
  const float* gender   = (const float*)d_in[2];
  const float* age      = (const float*)d_in[3];
  const float* z        = (const float*)d_in[4];
  const float* noise    = (const float*)d_in[5];
  const float* W_in     = (const float*)d_in[6];
  const float* b_in     = (const float*)d_in[7];
  const float* W_ih     = (const float*)d_in[8];
  const float* W_hh     = (const float*)d_in[9];
  const float* b_ih     = (const float*)d_in[10];
  const float* b_hh     = (const float*)d_in[11];
  const float* W_oq     = (const float*)d_in[12];
  const float* b_oq     = (const float*)d_in[13];
  const float* W_vg     = (const float*)d_in[14];
  const float* b_vg     = (const float*)d_in[15];
  const float* W_ug     = (const float*)d_in[16];
  const float* b_ug     = (const float*)d_in[17];
  const float* W_ff     = (const float*)d_in[18];
  const float* b_ff     = (const float*)d_in[19];
  const float* W_fb     = (const float*)d_in[20];
  const float* b_fb     = (const float*)d_in[21];
  const float* rev_ir   = (const float*)d_in[22];
  const float* wet_l    = (const float*)d_in[23];

  float* out = (float*)d_out;
  char* ws = (char*)d_ws;
  float* x      = (float*)(ws + OFF_X);
  float* gi     = (float*)(ws + OFF_GI);
  float* hs     = (float*)(ws + OFF_HS);
  float* filtR  = (float*)(ws + OFF_FILTR);
  float* oqw    = (float*)(ws + OFF_OQ);
  float* vgw    = (float*)(ws + OFF_VG);
  float* ugw    = (float*)(ws + OFF_UG);
  float* ffw    = (float*)(ws + OFF_FFW);
  float* fbw    = (float*)(ws + OFF_FBW);
  float* startw = (float*)(ws + OFF_START);
  float* f0m    = (float*)(ws + OFF_F0M);
  unsigned* bar_cnt = (unsigned*)(ws + OFF_BAR);
  unsigned* bar_gen = (unsigned*)(ws + OFF_BAR + 128);
  float* hbuf   = (float*)(ws + OFF_HBUF);
  float* exc    = (float*)(ws + OFF_EXC);
  float* audio  = (float*)(ws + OFF_AUDIO);

  // zero barrier + h double-buffer, and the padded audio accumulation buffer
  hipMemsetAsync(ws + OFF_BAR, 0, 256 + 16384, stream);
  hipMemsetAsync(ws + OFF_AUDIO, 0, (size_t)4 * AROW * 4, stream);

  k_f0mean<<<4, 256, 0, stream>>>(f0, f0m);
  k_inproj<<<512, 256, 0, stream>>>(f0, loud, gender, age, z, f0m, W_in, b_in, x);
  k_gemm_gi<<<dim3(24, 128), 256, 0, stream>>>(x, W_ih, b_ih, gi);
  k_gru<<<64, 256, 0, stream>>>(W_hh, b_hh, gi, hs, hbuf, bar_cnt, bar_gen);
  k_heads<<<8192, 256, 0, stream>>>(hs, W_oq, b_oq, W_vg, b_vg, W_ug, b_ug,
                                    W_ff, b_ff, W_fb, b_fb, out, oqw, vgw, ugw, ffw, fbw);
  k_scan<<<4, 256, 0, stream>>>(f0, startw);
  k_excite<<<8192, 256, 0, stream>>>(f0, noise, startw, oqw, vgw, ugw, exc);
  k_ir<<<8192, 256, 0, stream>>>(ffw, fbw, filtR);
  k_conv<<<8192, 256, 0, stream>>>(exc, filtR, audio);
  k_reverb<<<dim3(257, 4), 256, 0, stream>>>(audio, rev_ir, wet_l, out);
}

// Round 2
// 13227.785 us; speedup vs baseline: 1.6868x; 1.6868x over previous
//
#include <hip/hip_runtime.h>
#include <hip/hip_bf16.h>
#include <math.h>

// ---------------- constants ----------------
#define PI_F 3.14159265358979323846f
#define TWO_PI_F 6.283185307179586f

constexpr int BB = 4;            // batch
constexpr int FF_ = 2048;        // frames
constexpr int RC = 512;          // rnn channels
constexpr int HOP = 256;
constexpr int KK = 1024;         // FIR len
constexpr int LL = HOP + KK - 1; // 1279
constexpr size_t TOT = 525311;   // (F-1)*HOP + L
constexpr int APAD = 24064;      // zero pad in front of audio rows (>= REV-1, mult of 64)
constexpr size_t AROW = 549376;  // APAD + 525312
constexpr int REV = 24000;

// output offsets (floats)
constexpr size_t O1 = 2101244;   // oq
constexpr size_t O2 = 2109436;   // v_gain
constexpr size_t O3 = 2117628;   // u_gain
constexpr size_t O4 = 2125820;   // ff
constexpr size_t O5 = 2158588;   // fb

// workspace offsets (bytes)
constexpr size_t OFF_X      = 0;                 // 8192*512*4
constexpr size_t OFF_GI     = 16777216;          // 8192*1536*4
constexpr size_t OFF_HS     = 67108864;          // 8192*512*4
constexpr size_t OFF_FILTR  = 0;                 // 8192*1024*4 (overlays X/GI, dead by then)
constexpr size_t OFF_OQ     = 83886080;
constexpr size_t OFF_VG     = 83918848;
constexpr size_t OFF_UG     = 83951616;
constexpr size_t OFF_FFW    = 83984384;
constexpr size_t OFF_FBW    = 84115456;
constexpr size_t OFF_START  = 84246528;
constexpr size_t OFF_F0M    = 84279296;
constexpr size_t OFF_BAR    = 84279552;          // 4 counters, 64B apart (256B)
constexpr size_t OFF_HBUF   = 84279808;          // 2*2048 floats (16KB)
constexpr size_t OFF_EXC    = 84296192;          // 8192*256*4
constexpr size_t OFF_IRP    = 50331648;          // padded reverb ir (24064 floats) — in gi dead-zone, used after k_gru
constexpr size_t OFF_AUDIO  = 92684800;          // 4*549376*4

__device__ __forceinline__ float softplusf(float x) {
  return x > 20.0f ? x : log1pf(expf(x));
}
__device__ __forceinline__ float sigmoidf_(float x) {
  return 1.0f / (1.0f + expf(-x));
}

// ---------------- f0 mean per batch ----------------
__global__ __launch_bounds__(256) void k_f0mean(const float* __restrict__ f0, float* __restrict__ f0m) {
  int b = blockIdx.x, tid = threadIdx.x;
  float s = 0.f;
  for (int t = tid; t < FF_; t += 256) s += f0[b*FF_ + t];
  #pragma unroll
  for (int m = 1; m < 64; m <<= 1) s += __shfl_xor(s, m);
  __shared__ float ws4[4];
  if ((tid & 63) == 0) ws4[tid >> 6] = s;
  __syncthreads();
  if (tid == 0) f0m[b] = (ws4[0] + ws4[1] + ws4[2] + ws4[3]) * (1.0f / 2048.0f);
}

// ---------------- input projection: x = relu(concat @ W_in^T + b_in) ----------------
__global__ __launch_bounds__(256) void k_inproj(
    const float* __restrict__ f0, const float* __restrict__ loud,
    const float* __restrict__ gender, const float* __restrict__ age,
    const float* __restrict__ z, const float* __restrict__ f0m,
    const float* __restrict__ Win, const float* __restrict__ bin,
    float* __restrict__ x)
{
  __shared__ float inp[16 * 28];
  int r0 = blockIdx.x * 16;   // bf base
  int tid = threadIdx.x;
  for (int i = tid; i < 16 * 28; i += 256) {
    int r = i / 28, c = i % 28;
    int bf = r0 + r, b = bf >> 11;
    float v;
    if (c == 0)       v = f0[bf] - f0m[b];
    else if (c == 1)  v = loud[bf];
    else if (c < 4)   v = gender[(size_t)bf*2 + (c - 2)];
    else if (c < 12)  v = age[(size_t)bf*8 + (c - 4)];
    else              v = z[(size_t)bf*16 + (c - 12)];
    inp[i] = v;
  }
  __syncthreads();
  for (int o = tid; o < 16 * 512; o += 256) {
    int r = o >> 9, j = o & 511;
    const float* w = Win + j * 28;
    const float* ip = inp + r * 28;
    float a = bin[j];
    #pragma unroll
    for (int c2 = 0; c2 < 28; ++c2) a = fmaf(w[c2], ip[c2], a);
    x[(size_t)(r0 + r) * 512 + j] = fmaxf(a, 0.0f);
  }
}

// ---------------- GEMM: gi = x @ W_ih^T + b_ih  (M=8192, N=1536, K=512) ----------------
__global__ __launch_bounds__(256) void k_gemm_gi(
    const float* __restrict__ A, const float* __restrict__ Bw,
    const float* __restrict__ bias, float* __restrict__ C)
{
  __shared__ float As[32 * 68];
  __shared__ float Bs[32 * 68];
  int tid = threadIdx.x;
  int n0 = blockIdx.x * 64, m0 = blockIdx.y * 64;
  int tx = tid & 15, ty = tid >> 4;
  float c[4][4] = {{0.f}};
  for (int k0 = 0; k0 < 512; k0 += 32) {
    __syncthreads();
    for (int i = tid; i < 2048; i += 256) {
      int mm = i >> 5, kk = i & 31;
      As[kk * 68 + mm] = A[(size_t)(m0 + mm) * 512 + k0 + kk];
      Bs[kk * 68 + mm] = Bw[(size_t)(n0 + mm) * 512 + k0 + kk];
    }
    __syncthreads();
    #pragma unroll
    for (int kk = 0; kk < 32; ++kk) {
      float4 a = *(const float4*)&As[kk * 68 + ty * 4];
      float4 b = *(const float4*)&Bs[kk * 68 + tx * 4];
      c[0][0] = fmaf(a.x, b.x, c[0][0]); c[0][1] = fmaf(a.x, b.y, c[0][1]);
      c[0][2] = fmaf(a.x, b.z, c[0][2]); c[0][3] = fmaf(a.x, b.w, c[0][3]);
      c[1][0] = fmaf(a.y, b.x, c[1][0]); c[1][1] = fmaf(a.y, b.y, c[1][1]);
      c[1][2] = fmaf(a.y, b.z, c[1][2]); c[1][3] = fmaf(a.y, b.w, c[1][3]);
      c[2][0] = fmaf(a.z, b.x, c[2][0]); c[2][1] = fmaf(a.z, b.y, c[2][1]);
      c[2][2] = fmaf(a.z, b.z, c[2][2]); c[2][3] = fmaf(a.z, b.w, c[2][3]);
      c[3][0] = fmaf(a.w, b.x, c[3][0]); c[3][1] = fmaf(a.w, b.y, c[3][1]);
      c[3][2] = fmaf(a.w, b.z, c[3][2]); c[3][3] = fmaf(a.w, b.w, c[3][3]);
    }
  }
  int n = n0 + tx * 4;
  float4 bb = *(const float4*)&bias[n];
  #pragma unroll
  for (int mi = 0; mi < 4; ++mi) {
    int m = m0 + ty * 4 + mi;
    float4 v;
    v.x = c[mi][0] + bb.x; v.y = c[mi][1] + bb.y;
    v.z = c[mi][2] + bb.z; v.w = c[mi][3] + bb.w;
    *(float4*)&C[(size_t)m * 1536 + n] = v;
  }
}

// ---------------- persistent GRU v2 ----------------
// 4 independent barrier groups (one per batch) x 16 WGs (32 units each).
// bf16 W_hh in LDS (row stride 516 to break bank aliasing), monotonic arrive
// counter, relaxed agent-scope atomics only (no device fences -> no wbL2).
__global__ __launch_bounds__(256) void k_gru(
    const float* __restrict__ Whh, const float* __restrict__ bhh,
    const float* __restrict__ gi, float* __restrict__ hs,
    float* hbuf, unsigned* bars)
{
  __shared__ unsigned short wlds[96 * 516];  // 99072 B
  __shared__ float hs_[512];
  __shared__ float red[192];
  __shared__ float bhh_s[96];

  const int tid = threadIdx.x;
  const int b   = blockIdx.x & 3;       // batch / barrier group
  const int wgi = blockIdx.x >> 2;      // 0..15
  const int u0  = wgi * 32;
  unsigned* cnt = bars + b * 16;        // 64B apart

  // stage W_hh rows (3 gates x 32 units) as bf16 (RNE)
  for (int i = tid; i < 96 * 512; i += 256) {
    int r = i >> 9, k = i & 511;
    int g3 = r >> 5, u = r & 31;
    union { float f; unsigned u32; } cv;
    cv.f = Whh[(size_t)(g3 * 512 + u0 + u) * 512 + k];
    unsigned xbits = cv.u32;
    unsigned rnd = (xbits + 0x7FFFu + ((xbits >> 16) & 1u)) >> 16;
    wlds[r * 516 + k] = (unsigned short)rnd;
  }
  if (tid < 96) {
    int g3 = tid >> 5, u = tid & 31;
    bhh_s[tid] = bhh[g3 * 512 + u0 + u];
  }
  __syncthreads();

  const int row = tid >> 1;   // 0..95 (active when tid<192)
  const int kh  = tid & 1;

  #pragma unroll 1
  for (unsigned t = 0; t < 2048; ++t) {
    const int slot = (int)(t & 1u);
    // gi prefetch for this step (independent of barrier)
    float gir = 0.f, giz = 0.f, gin = 0.f;
    if (tid < 32) {
      const float* gp = gi + (size_t)(b * 2048 + (int)t) * 1536 + u0 + tid;
      gir = gp[0]; giz = gp[512]; gin = gp[1024];
    }
    // wait until all 16 WGs of this group finished step t-1
    if (t > 0) {
      const unsigned target = 16u * t;
      while (__hip_atomic_load(cnt, __ATOMIC_RELAXED, __HIP_MEMORY_SCOPE_AGENT) < target)
        __builtin_amdgcn_s_sleep(1);
    }
    // load h_t (512 floats for this batch) into LDS
    {
      unsigned long long hv = __hip_atomic_load(
          (const unsigned long long*)(hbuf + (size_t)slot * 2048 + b * 512 + 2 * tid),
          __ATOMIC_RELAXED, __HIP_MEMORY_SCOPE_AGENT);
      union { unsigned long long q; float f[2]; } cv; cv.q = hv;
      hs_[2 * tid]     = cv.f[0];
      hs_[2 * tid + 1] = cv.f[1];
    }
    __syncthreads();
    // partial dots: 96 rows x 2 k-halves
    if (tid < 192) {
      const unsigned short* wp = wlds + row * 516 + kh * 256;
      const float* hp = hs_ + kh * 256;
      float part = 0.f;
      #pragma unroll 16
      for (int k = 0; k < 256; k += 4) {
        uint2 w4 = *(const uint2*)(wp + k);
        float4 h4 = *(const float4*)(hp + k);
        union { unsigned u; float f; } c0, c1, c2, c3;
        c0.u = w4.x << 16; c1.u = w4.x & 0xFFFF0000u;
        c2.u = w4.y << 16; c3.u = w4.y & 0xFFFF0000u;
        part = fmaf(c0.f, h4.x, part); part = fmaf(c1.f, h4.y, part);
        part = fmaf(c2.f, h4.z, part); part = fmaf(c3.f, h4.w, part);
      }
      red[tid] = part;
    }
    __syncthreads();
    // cell update in wave 0 (lanes 0..31)
    if (tid < 32) {
      float ghr = red[tid * 2]        + red[tid * 2 + 1]        + bhh_s[tid];
      float ghz = red[(32 + tid) * 2] + red[(32 + tid) * 2 + 1] + bhh_s[32 + tid];
      float ghn = red[(64 + tid) * 2] + red[(64 + tid) * 2 + 1] + bhh_s[64 + tid];
      float r  = sigmoidf_(gir + ghr);
      float zg = sigmoidf_(giz + ghz);
      float n  = tanhf(gin + r * ghn);
      float hold = hs_[u0 + tid];
      float hnew = (1.0f - zg) * n + zg * hold;
      hs[(size_t)(b * 2048 + (int)t) * 512 + u0 + tid] = hnew;
      __hip_atomic_store(hbuf + (size_t)(slot ^ 1) * 2048 + b * 512 + u0 + tid, hnew,
                         __ATOMIC_RELAXED, __HIP_MEMORY_SCOPE_AGENT);
    }
    asm volatile("s_waitcnt vmcnt(0)" ::: "memory");
    if (tid == 0)
      __hip_atomic_fetch_add(cnt, 1u, __ATOMIC_RELAXED, __HIP_MEMORY_SCOPE_AGENT);
    // no trailing __syncthreads: next-iter LDS writes are gated by the poll,
    // which cannot pass until our own tid0 (wave 0) has arrived.
  }
}

// ---------------- heads: oq, v_gain, u_gain, ff(cumsum), fb ----------------
__global__ __launch_bounds__(256) void k_heads(
    const float* __restrict__ hs,
    const float* __restrict__ Woq, const float* __restrict__ boq,
    const float* __restrict__ Wvg, const float* __restrict__ bvg,
    const float* __restrict__ Wug, const float* __restrict__ bug,
    const float* __restrict__ Wff, const float* __restrict__ bff,
    const float* __restrict__ Wfb, const float* __restrict__ bfb,
    float* __restrict__ out,
    float* __restrict__ oqw, float* __restrict__ vgw, float* __restrict__ ugw,
    float* __restrict__ ffw, float* __restrict__ fbw)
{
  int bf = blockIdx.x, tid = threadIdx.x;
  const float* h = hs + (size_t)bf * 512;
  float p[11];
  #pragma unroll
  for (int i = 0; i < 11; ++i) p[i] = 0.f;
  for (int k = tid; k < 512; k += 256) {
    float hv = h[k];
    p[0] = fmaf(Woq[k], hv, p[0]);
    p[1] = fmaf(Wvg[k], hv, p[1]);
    p[2] = fmaf(Wug[k], hv, p[2]);
    p[3] = fmaf(Wff[k], hv, p[3]);
    p[4] = fmaf(Wff[512 + k], hv, p[4]);
    p[5] = fmaf(Wff[1024 + k], hv, p[5]);
    p[6] = fmaf(Wff[1536 + k], hv, p[6]);
    p[7] = fmaf(Wfb[k], hv, p[7]);
    p[8] = fmaf(Wfb[512 + k], hv, p[8]);
    p[9] = fmaf(Wfb[1024 + k], hv, p[9]);
    p[10] = fmaf(Wfb[1536 + k], hv, p[10]);
  }
  #pragma unroll
  for (int i = 0; i < 11; ++i) {
    float v = p[i];
    #pragma unroll
    for (int m = 1; m < 64; m <<= 1) v += __shfl_xor(v, m);
    p[i] = v;
  }
  __shared__ float r4[4][11];
  if ((tid & 63) == 0) {
    int w = tid >> 6;
    #pragma unroll
    for (int i = 0; i < 11; ++i) r4[w][i] = p[i];
  }
  __syncthreads();
  if (tid == 0) {
    float s[11];
    #pragma unroll
    for (int i = 0; i < 11; ++i) s[i] = r4[0][i] + r4[1][i] + r4[2][i] + r4[3][i];
    float oqv = sigmoidf_(s[0] + boq[0]);
    float vg = softplusf(s[1] + bvg[0]);
    float ug = softplusf(s[2] + bug[0]);
    out[O1 + bf] = oqv; oqw[bf] = oqv;
    out[O2 + bf] = vg;  vgw[bf] = vg;
    out[O3 + bf] = ug;  ugw[bf] = ug;
    float run = 200.0f;
    #pragma unroll
    for (int j = 0; j < 4; ++j) {
      run += softplusf(s[3 + j] + bff[j]);
      out[O4 + (size_t)bf * 4 + j] = run; ffw[(size_t)bf * 4 + j] = run;
    }
    #pragma unroll
    for (int j = 0; j < 4; ++j) {
      float g = softplusf(s[7 + j] + bfb[j]) + 50.0f;
      out[O5 + (size_t)bf * 4 + j] = g; fbw[(size_t)bf * 4 + j] = g;
    }
  }
}

// ---------------- per-batch prefix scan of cycles -> start phase ----------------
__global__ __launch_bounds__(256) void k_scan(const float* __restrict__ f0, float* __restrict__ startw) {
  __shared__ float ts[256];
  int b = blockIdx.x, tid = threadIdx.x;
  const float CY = 256.0f / 24000.0f;
  float c[8], run = 0.f;
  int base = b * 2048 + tid * 8;
  #pragma unroll
  for (int j = 0; j < 8; ++j) { c[j] = run; run += f0[base + j] * CY; }
  ts[tid] = run;
  __syncthreads();
  for (int off = 1; off < 256; off <<= 1) {
    float v = (tid >= off) ? ts[tid - off] : 0.0f;
    __syncthreads();
    ts[tid] += v;
    __syncthreads();
  }
  float excl = (tid == 0) ? 0.0f : ts[tid - 1];
  #pragma unroll
  for (int j = 0; j < 8; ++j) {
    float st = excl + c[j];
    startw[base + j] = st - floorf(st);
  }
}

// ---------------- glottal source + excitation ----------------
__global__ __launch_bounds__(256) void k_excite(
    const float* __restrict__ f0, const float* __restrict__ noise,
    const float* __restrict__ startw, const float* __restrict__ oqw,
    const float* __restrict__ vgw, const float* __restrict__ ugw,
    float* __restrict__ exc)
{
  int bf = blockIdx.x, i = threadIdx.x;
  float st = startw[bf], f0v = f0[bf], oqv = oqw[bf], vg = vgw[bf], ug = ugw[bf];
  float total = st + f0v * ((float)i * (1.0f / 24000.0f));
  float phi = total - floorf(total);
  float peak = oqv * 0.66f;
  float rise = 0.5f * (1.0f - cosf(PI_F * phi / (peak + 1e-6f)));
  float fall = cosf(PI_F * (phi - peak) / (2.0f * (oqv - peak) + 1e-6f));
  float v = (phi < peak) ? rise : ((phi < oqv) ? fall : 0.0f);
  exc[(size_t)bf * 256 + i] = v * vg + noise[(size_t)bf * 256 + i] * ug;
}

// ---------------- formant IR generation + normalization (stored reversed) ----------------
__global__ __launch_bounds__(256) void k_ir(
    const float* __restrict__ ffw, const float* __restrict__ fbw,
    float* __restrict__ filtR)
{
  __shared__ float ffs[4], fbs[4], ssc[1], wmax[4];
  int bf = blockIdx.x, tid = threadIdx.x;
  if (tid < 4) { ffs[tid] = ffw[(size_t)bf * 4 + tid]; fbs[tid] = fbw[(size_t)bf * 4 + tid]; }
  __syncthreads();
  float vals[4];
  float am = 0.f;
  #pragma unroll
  for (int it = 0; it < 4; ++it) {
    int k = it * 256 + tid;
    float t = (float)k * (1.0f / 24000.0f);
    float s = 0.f;
    #pragma unroll
    for (int j = 0; j < 4; ++j)
      s += expf(-PI_F * fbs[j] * t) * sinf(TWO_PI_F * ffs[j] * t);
    vals[it] = s;
    am = fmaxf(am, fabsf(s));
  }
  #pragma unroll
  for (int m = 1; m < 64; m <<= 1) am = fmaxf(am, __shfl_xor(am, m));
  if ((tid & 63) == 0) wmax[tid >> 6] = am;
  __syncthreads();
  if (tid == 0) ssc[0] = fmaxf(fmaxf(wmax[0], wmax[1]), fmaxf(wmax[2], wmax[3])) + 1e-8f;
  __syncthreads();
  float inv = 1.0f / ssc[0];
  #pragma unroll
  for (int it = 0; it < 4; ++it) {
    int k = it * 256 + tid;
    filtR[(size_t)bf * 1024 + (1023 - k)] = vals[it] * inv;
  }
}

// ---------------- per-frame FIR conv (full) + overlap-add via atomics ----------------
__global__ __launch_bounds__(256) void k_conv(
    const float* __restrict__ exc, const float* __restrict__ filtR,
    float* __restrict__ audio)
{
  __shared__ float es[256];
  __shared__ float fp[1536];
  int bf = blockIdx.x, tid = threadIdx.x;
  int b = bf >> 11, f = bf & 2047;
  es[tid] = exc[(size_t)bf * 256 + tid];
  for (int i = tid; i < 1536; i += 256) {
    int j = i - 256;
    fp[i] = (j >= 0 && j < 1024) ? filtR[(size_t)bf * 1024 + j] : 0.0f;
  }
  __syncthreads();
  int n0 = tid * 5;
  float V0 = fp[n0 + 256], V1 = fp[n0 + 257], V2 = fp[n0 + 258], V3 = fp[n0 + 259], V4 = fp[n0 + 260];
  float a0 = 0.f, a1 = 0.f, a2 = 0.f, a3 = 0.f, a4 = 0.f;
  #pragma unroll 4
  for (int m = 0; m < 256; ++m) {
    float e = es[m];
    a0 = fmaf(e, V0, a0); a1 = fmaf(e, V1, a1); a2 = fmaf(e, V2, a2);
    a3 = fmaf(e, V3, a3); a4 = fmaf(e, V4, a4);
    V4 = V3; V3 = V2; V2 = V1; V1 = V0;
    V0 = fp[n0 + 255 - m];
  }
  float* arow = audio + (size_t)b * AROW + APAD + (size_t)f * 256;
  if (n0 + 0 < LL) atomicAdd(&arow[n0 + 0], a0);
  if (n0 + 1 < LL) atomicAdd(&arow[n0 + 1], a1);
  if (n0 + 2 < LL) atomicAdd(&arow[n0 + 2], a2);
  if (n0 + 3 < LL) atomicAdd(&arow[n0 + 3], a3);
  if (n0 + 4 < LL) atomicAdd(&arow[n0 + 4], a4);
}

// ---------------- pad reverb ir to 24064 with zeros ----------------
__global__ __launch_bounds__(256) void k_padir(const float* __restrict__ ir, float* __restrict__ irp) {
  int i = blockIdx.x * 256 + threadIdx.x;
  if (i < 24064) irp[i] = (i < REV) ? ir[i] : 0.0f;
}

// ---------------- reverb FIR (24000 taps) + wet/dry mix ----------------
// ir taps read via wave-uniform global loads (scalarize to s_load + v_fma w/ sgpr)
__global__ __launch_bounds__(256) void k_reverb(
    const float* __restrict__ audio, const float* __restrict__ irp,
    const float* __restrict__ wetl, float* __restrict__ out)
{
  __shared__ float as_[2376];   // 2304 window + swizzle pad
  int tb = blockIdx.x, b = blockIdx.y, tid = threadIdx.x;
  int tbase = tb * 2048;
  const float* arow = audio + (size_t)b * AROW;
  float acc[8];
  #pragma unroll
  for (int j = 0; j < 8; ++j) acc[j] = 0.f;

  for (int c = 0; c < 94; ++c) {
    __syncthreads();
    int B0 = APAD + tbase - c * 256 - 256;   // >= 0 always
    for (int i = tid; i < 2304; i += 256) {
      int g = B0 + i;
      float v = (g < (int)AROW) ? arow[g] : 0.0f;
      as_[i + (i >> 5)] = v;
    }
    __syncthreads();
    const float* irc = irp + c * 256;        // uniform -> scalar loads
    int base = 8 * tid + 256;
    int li;
    li = base + 0; float V0 = as_[li + (li >> 5)];
    li = base + 1; float V1 = as_[li + (li >> 5)];
    li = base + 2; float V2 = as_[li + (li >> 5)];
    li = base + 3; float V3 = as_[li + (li >> 5)];
    li = base + 4; float V4 = as_[li + (li >> 5)];
    li = base + 5; float V5 = as_[li + (li >> 5)];
    li = base + 6; float V6 = as_[li + (li >> 5)];
    li = base + 7; float V7 = as_[li + (li >> 5)];
    #pragma unroll 16
    for (int rr = 0; rr < 256; ++rr) {
      float w = irc[rr];
      acc[0] = fmaf(w, V0, acc[0]); acc[1] = fmaf(w, V1, acc[1]);
      acc[2] = fmaf(w, V2, acc[2]); acc[3] = fmaf(w, V3, acc[3]);
      acc[4] = fmaf(w, V4, acc[4]); acc[5] = fmaf(w, V5, acc[5]);
      acc[6] = fmaf(w, V6, acc[6]); acc[7] = fmaf(w, V7, acc[7]);
      V7 = V6; V6 = V5; V5 = V4; V4 = V3; V3 = V2; V2 = V1; V1 = V0;
      int ln = base - 1 - rr;
      V0 = as_[ln + (ln >> 5)];
    }
  }
  float wet = sigmoidf_(wetl[0]);
  #pragma unroll
  for (int j = 0; j < 8; ++j) {
    long t = (long)tbase + 8 * tid + j;
    if (t < (long)TOT) {
      float av = arow[APAD + t];
      out[(size_t)b * TOT + t] = (1.0f - wet) * av + wet * acc[j];
    }
  }
}

// ---------------- launch ----------------
extern "C" void kernel_launch(void* const* d_in, const int* in_sizes, int n_in,
                              void* d_out, int out_size, void* d_ws, size_t ws_size,
                              hipStream_t stream) {
  const float* f0       = (const float*)d_in[0];
  const float* loud     = (const float*)d_in[1];
  const float* gender   = (const float*)d_in[2];
  const float* age      = (const float*)d_in[3];
  const float* z        = (const float*)d_in[4];
  const float* noise    = (const float*)d_in[5];
  const float* W_in     = (const float*)d_in[6];
  const float* b_in     = (const float*)d_in[7];
  const float* W_ih     = (const float*)d_in[8];
  const float* W_hh     = (const float*)d_in[9];
  const float* b_ih     = (const float*)d_in[10];
  const float* b_hh     = (const float*)d_in[11];
  const float* W_oq     = (const float*)d_in[12];
  const float* b_oq     = (const float*)d_in[13];
  const float* W_vg     = (const float*)d_in[14];
  const float* b_vg     = (const float*)d_in[15];
  const float* W_ug     = (const float*)d_in[16];
  const float* b_ug     = (const float*)d_in[17];
  const float* W_ff     = (const float*)d_in[18];
  const float* b_ff     = (const float*)d_in[19];
  const float* W_fb     = (const float*)d_in[20];
  const float* b_fb     = (const float*)d_in[21];
  const float* rev_ir   = (const float*)d_in[22];
  const float* wet_l    = (const float*)d_in[23];

  float* out = (float*)d_out;
  char* ws = (char*)d_ws;
  float* x      = (float*)(ws + OFF_X);
  float* gi     = (float*)(ws + OFF_GI);
  float* hs     = (float*)(ws + OFF_HS);
  float* filtR  = (float*)(ws + OFF_FILTR);
  float* oqw    = (float*)(ws + OFF_OQ);
  float* vgw    = (float*)(ws + OFF_VG);
  float* ugw    = (float*)(ws + OFF_UG);
  float* ffw    = (float*)(ws + OFF_FFW);
  float* fbw    = (float*)(ws + OFF_FBW);
  float* startw = (float*)(ws + OFF_START);
  float* f0m    = (float*)(ws + OFF_F0M);
  unsigned* bars = (unsigned*)(ws + OFF_BAR);
  float* hbuf   = (float*)(ws + OFF_HBUF);
  float* exc    = (float*)(ws + OFF_EXC);
  float* irp    = (float*)(ws + OFF_IRP);
  float* audio  = (float*)(ws + OFF_AUDIO);

  // zero barrier counters + h double-buffer, and the padded audio accumulator
  hipMemsetAsync(ws + OFF_BAR, 0, 256 + 16384, stream);
  hipMemsetAsync(ws + OFF_AUDIO, 0, (size_t)4 * AROW * 4, stream);

  k_f0mean<<<4, 256, 0, stream>>>(f0, f0m);
  k_inproj<<<512, 256, 0, stream>>>(f0, loud, gender, age, z, f0m, W_in, b_in, x);
  k_gemm_gi<<<dim3(24, 128), 256, 0, stream>>>(x, W_ih, b_ih, gi);
  k_gru<<<64, 256, 0, stream>>>(W_hh, b_hh, gi, hs, hbuf, bars);
  k_heads<<<8192, 256, 0, stream>>>(hs, W_oq, b_oq, W_vg, b_vg, W_ug, b_ug,
                                    W_ff, b_ff, W_fb, b_fb, out, oqw, vgw, ugw, ffw, fbw);
  k_scan<<<4, 256, 0, stream>>>(f0, startw);
  k_excite<<<8192, 256, 0, stream>>>(f0, noise, startw, oqw, vgw, ugw, exc);
  k_ir<<<8192, 256, 0, stream>>>(ffw, fbw, filtR);
  k_conv<<<8192, 256, 0, stream>>>(exc, filtR, audio);
  k_padir<<<94, 256, 0, stream>>>(rev_ir, irp);   // gi region dead after k_gru
  k_reverb<<<dim3(257, 4), 256, 0, stream>>>(audio, irp, wet_l, out);
}

// Round 4
// 7373.740 us; speedup vs baseline: 3.0260x; 1.7939x over previous
//
#include <hip/hip_runtime.h>
#include <hip/hip_bf16.h>
#include <math.h>

// ---------------- constants ----------------
#define PI_F 3.14159265358979323846f
#define TWO_PI_F 6.283185307179586f

constexpr int BB = 4;            // batch
constexpr int FF_ = 2048;        // frames
constexpr int RC = 512;          // rnn channels
constexpr int HOP = 256;
constexpr int KK = 1024;         // FIR len
constexpr int LL = HOP + KK - 1; // 1279
constexpr size_t TOT = 525311;   // (F-1)*HOP + L
constexpr int APAD = 24064;      // zero pad in front of audio rows (>= REV-1, mult of 64)
constexpr size_t AROW = 549376;  // APAD + 525312
constexpr int REV = 24000;

// output offsets (floats)
constexpr size_t O1 = 2101244;   // oq
constexpr size_t O2 = 2109436;   // v_gain
constexpr size_t O3 = 2117628;   // u_gain
constexpr size_t O4 = 2125820;   // ff
constexpr size_t O5 = 2158588;   // fb

// workspace offsets (bytes)
constexpr size_t OFF_X      = 0;                 // 8192*512*4
constexpr size_t OFF_GI     = 16777216;          // 8192*1536*4
constexpr size_t OFF_HS     = 67108864;          // 8192*512*4
constexpr size_t OFF_FILTR  = 0;                 // 8192*1024*4 (overlays X/GI, dead by then)
constexpr size_t OFF_OQ     = 83886080;
constexpr size_t OFF_VG     = 83918848;
constexpr size_t OFF_UG     = 83951616;
constexpr size_t OFF_FFW    = 83984384;          // also hbuf (32KB) during k_gru; ffw written after
constexpr size_t OFF_FBW    = 84115456;
constexpr size_t OFF_START  = 84246528;
constexpr size_t OFF_F0M    = 84279296;
constexpr size_t OFF_EXC    = 84296192;          // 8192*256*4
constexpr size_t OFF_IRP    = 50331648;          // padded reverb ir — in gi dead-zone, used after k_gru
constexpr size_t OFF_AUDIO  = 92684800;          // 4*549376*4

constexpr size_t OFF_HBUF   = OFF_FFW;           // 2 slots x 4 batch x 512 units x 8B = 32KB

__device__ __forceinline__ float softplusf(float x) {
  return x > 20.0f ? x : log1pf(expf(x));
}
__device__ __forceinline__ float sigmoidf_(float x) {
  return 1.0f / (1.0f + expf(-x));
}

typedef _Float16 half2v __attribute__((ext_vector_type(2)));

__device__ __forceinline__ float dot2f(unsigned wa, unsigned hb, float acc) {
#if __has_builtin(__builtin_amdgcn_fdot2)
  union { unsigned u; half2v h; } A, B;
  A.u = wa; B.u = hb;
  return __builtin_amdgcn_fdot2(A.h, B.h, acc, false);
#else
  union { unsigned u; _Float16 h[2]; } A, B;
  A.u = wa; B.u = hb;
  return fmaf((float)A.h[0], (float)B.h[0], fmaf((float)A.h[1], (float)B.h[1], acc));
#endif
}

// ---------------- f0 mean per batch ----------------
__global__ __launch_bounds__(256) void k_f0mean(const float* __restrict__ f0, float* __restrict__ f0m) {
  int b = blockIdx.x, tid = threadIdx.x;
  float s = 0.f;
  for (int t = tid; t < FF_; t += 256) s += f0[b*FF_ + t];
  #pragma unroll
  for (int m = 1; m < 64; m <<= 1) s += __shfl_xor(s, m);
  __shared__ float ws4[4];
  if ((tid & 63) == 0) ws4[tid >> 6] = s;
  __syncthreads();
  if (tid == 0) f0m[b] = (ws4[0] + ws4[1] + ws4[2] + ws4[3]) * (1.0f / 2048.0f);
}

// ---------------- input projection: x = relu(concat @ W_in^T + b_in) ----------------
__global__ __launch_bounds__(256) void k_inproj(
    const float* __restrict__ f0, const float* __restrict__ loud,
    const float* __restrict__ gender, const float* __restrict__ age,
    const float* __restrict__ z, const float* __restrict__ f0m,
    const float* __restrict__ Win, const float* __restrict__ bin,
    float* __restrict__ x)
{
  __shared__ float inp[16 * 28];
  int r0 = blockIdx.x * 16;   // bf base
  int tid = threadIdx.x;
  for (int i = tid; i < 16 * 28; i += 256) {
    int r = i / 28, c = i % 28;
    int bf = r0 + r, b = bf >> 11;
    float v;
    if (c == 0)       v = f0[bf] - f0m[b];
    else if (c == 1)  v = loud[bf];
    else if (c < 4)   v = gender[(size_t)bf*2 + (c - 2)];
    else if (c < 12)  v = age[(size_t)bf*8 + (c - 4)];
    else              v = z[(size_t)bf*16 + (c - 12)];
    inp[i] = v;
  }
  __syncthreads();
  for (int o = tid; o < 16 * 512; o += 256) {
    int r = o >> 9, j = o & 511;
    const float* w = Win + j * 28;
    const float* ip = inp + r * 28;
    float a = bin[j];
    #pragma unroll
    for (int c2 = 0; c2 < 28; ++c2) a = fmaf(w[c2], ip[c2], a);
    x[(size_t)(r0 + r) * 512 + j] = fmaxf(a, 0.0f);
  }
}

// ---------------- GEMM: gi = x @ W_ih^T + b_ih  (M=8192, N=1536, K=512) ----------------
__global__ __launch_bounds__(256) void k_gemm_gi(
    const float* __restrict__ A, const float* __restrict__ Bw,
    const float* __restrict__ bias, float* __restrict__ C)
{
  __shared__ float As[32 * 68];
  __shared__ float Bs[32 * 68];
  int tid = threadIdx.x;
  int n0 = blockIdx.x * 64, m0 = blockIdx.y * 64;
  int tx = tid & 15, ty = tid >> 4;
  float c[4][4] = {{0.f}};
  for (int k0 = 0; k0 < 512; k0 += 32) {
    __syncthreads();
    for (int i = tid; i < 2048; i += 256) {
      int mm = i >> 5, kk = i & 31;
      As[kk * 68 + mm] = A[(size_t)(m0 + mm) * 512 + k0 + kk];
      Bs[kk * 68 + mm] = Bw[(size_t)(n0 + mm) * 512 + k0 + kk];
    }
    __syncthreads();
    #pragma unroll
    for (int kk = 0; kk < 32; ++kk) {
      float4 a = *(const float4*)&As[kk * 68 + ty * 4];
      float4 b = *(const float4*)&Bs[kk * 68 + tx * 4];
      c[0][0] = fmaf(a.x, b.x, c[0][0]); c[0][1] = fmaf(a.x, b.y, c[0][1]);
      c[0][2] = fmaf(a.x, b.z, c[0][2]); c[0][3] = fmaf(a.x, b.w, c[0][3]);
      c[1][0] = fmaf(a.y, b.x, c[1][0]); c[1][1] = fmaf(a.y, b.y, c[1][1]);
      c[1][2] = fmaf(a.y, b.z, c[1][2]); c[1][3] = fmaf(a.y, b.w, c[1][3]);
      c[2][0] = fmaf(a.z, b.x, c[2][0]); c[2][1] = fmaf(a.z, b.y, c[2][1]);
      c[2][2] = fmaf(a.z, b.z, c[2][2]); c[2][3] = fmaf(a.z, b.w, c[2][3]);
      c[3][0] = fmaf(a.w, b.x, c[3][0]); c[3][1] = fmaf(a.w, b.y, c[3][1]);
      c[3][2] = fmaf(a.w, b.z, c[3][2]); c[3][3] = fmaf(a.w, b.w, c[3][3]);
    }
  }
  int n = n0 + tx * 4;
  float4 bb = *(const float4*)&bias[n];
  #pragma unroll
  for (int mi = 0; mi < 4; ++mi) {
    int m = m0 + ty * 4 + mi;
    float4 v;
    v.x = c[mi][0] + bb.x; v.y = c[mi][1] + bb.y;
    v.z = c[mi][2] + bb.z; v.w = c[mi][3] + bb.w;
    *(float4*)&C[(size_t)m * 1536 + n] = v;
  }
}

// ---------------- persistent GRU v3.1 ----------------
// 4 independent groups (one per batch) x 16 WGs (32 units each).
// Sync: each h value packed {fp32, step-tag} in one 8B word, stored with a
// single relaxed agent-scope atomic. Consumers poll the data words directly:
// tag==t implies value valid. The tag IS the barrier. One L3 trip per step.
// Weights: f16 in LDS, per-(row,half) contiguous 132-dword blocks (b128 reads
// at the 8-cycle bank floor). Inner loop: v_dot2_f32_f16.
// v3.1 fix: hs2 half-stride is 132 (128 pairs + pad), was 68 (OOB into red).
__global__ __launch_bounds__(256) void k_gru(
    const float* __restrict__ Whh, const float* __restrict__ bhh,
    const float* __restrict__ gi, float* __restrict__ hs,
    unsigned long long* hbuf)
{
  __shared__ unsigned wlds[192 * 132];  // f16 pairs: (row,half) blocks, 101376B
  __shared__ float hs_[512];            // fp32 h (state precision)
  __shared__ unsigned hs2[2 * 132];     // f16-pair copy of h, per half (128 pairs + pad)
  __shared__ float red[192];
  __shared__ float ghl[96];
  __shared__ float bhh_s[96];

  const int tid = threadIdx.x;
  const int b   = blockIdx.x & 3;       // batch / group
  const int wgi = blockIdx.x >> 2;      // 0..15
  const int u0  = wgi * 32;

  // stage W_hh rows (3 gates x 32 units) as f16 pairs
  for (int p = tid; p < 96 * 256; p += 256) {
    int row = p >> 8, pr = p & 255;     // pr: k-pair index 0..255
    int g3 = row >> 5, u = row & 31;
    const float* srcw = Whh + (size_t)(g3 * 512 + u0 + u) * 512 + 2 * pr;
    union { unsigned u32; _Float16 h[2]; } cv;
    cv.h[0] = (_Float16)srcw[0];
    cv.h[1] = (_Float16)srcw[1];
    int kh = pr >> 7, j = pr & 127;
    wlds[(row * 2 + kh) * 132 + j] = cv.u32;
  }
  if (tid < 96) {
    int g3 = tid >> 5, u = tid & 31;
    bhh_s[tid] = bhh[g3 * 512 + u0 + u];
  }
  __syncthreads();

  const int kh = tid & 1;               // for dot threads (tid<192): row=tid>>1

  #pragma unroll 1
  for (unsigned t = 0; t < 2048; ++t) {
    // gi prefetch for this step (independent of sync)
    float gir = 0.f, giz = 0.f, gin = 0.f;
    if (tid < 32) {
      const float* gp = gi + (size_t)(b * 2048 + (int)t) * 1536 + u0 + tid;
      gir = gp[0]; giz = gp[512]; gin = gp[1024];
    }
    // poll own 2 units of h_t (tag == t), slot = t&1
    {
      const unsigned long long* pp =
          hbuf + ((size_t)(t & 1u) * 4 + b) * 512 + 2 * tid;
      unsigned long long w0 = __hip_atomic_load(pp,     __ATOMIC_RELAXED, __HIP_MEMORY_SCOPE_AGENT);
      unsigned long long w1 = __hip_atomic_load(pp + 1, __ATOMIC_RELAXED, __HIP_MEMORY_SCOPE_AGENT);
      while ((unsigned)(w0 >> 32) != t)
        w0 = __hip_atomic_load(pp,     __ATOMIC_RELAXED, __HIP_MEMORY_SCOPE_AGENT);
      while ((unsigned)(w1 >> 32) != t)
        w1 = __hip_atomic_load(pp + 1, __ATOMIC_RELAXED, __HIP_MEMORY_SCOPE_AGENT);
      union { unsigned u; float f; } c0, c1;
      c0.u = (unsigned)w0; c1.u = (unsigned)w1;
      *(float2*)&hs_[2 * tid] = make_float2(c0.f, c1.f);
      union { unsigned u32; _Float16 h[2]; } pk;
      pk.h[0] = (_Float16)c0.f; pk.h[1] = (_Float16)c1.f;
      hs2[(tid >> 7) * 132 + (tid & 127)] = pk.u32;
    }
    __syncthreads();
    // partial dots: 96 rows x 2 k-halves, f16 dot2
    if (tid < 192) {
      const unsigned* wp = wlds + tid * 132;
      const unsigned* hp = hs2 + kh * 132;
      float part = 0.f;
      #pragma unroll 8
      for (int i = 0; i < 32; ++i) {
        uint4 w4 = *(const uint4*)(wp + 4 * i);
        uint4 h4 = *(const uint4*)(hp + 4 * i);
        part = dot2f(w4.x, h4.x, part);
        part = dot2f(w4.y, h4.y, part);
        part = dot2f(w4.z, h4.z, part);
        part = dot2f(w4.w, h4.w, part);
      }
      red[tid] = part;
    }
    __syncthreads();
    if (tid < 96) {
      ghl[tid] = red[2 * tid] + red[2 * tid + 1] + bhh_s[tid];
    }
    __syncthreads();
    // cell update + publish (wave 0, lanes 0..31)
    if (tid < 32) {
      float ghr = ghl[tid];
      float ghz = ghl[32 + tid];
      float ghn = ghl[64 + tid];
      float r  = sigmoidf_(gir + ghr);
      float zg = sigmoidf_(giz + ghz);
      float n  = tanhf(gin + r * ghn);
      float hold = hs_[u0 + tid];
      float hnew = (1.0f - zg) * n + zg * hold;
      hs[(size_t)(b * 2048 + (int)t) * 512 + u0 + tid] = hnew;
      union { unsigned long long q; struct { float v; unsigned tg; } s; } pk;
      pk.s.v = hnew; pk.s.tg = t + 1u;
      __hip_atomic_store(hbuf + ((size_t)((t + 1u) & 1u) * 4 + b) * 512 + u0 + tid,
                         pk.q, __ATOMIC_RELAXED, __HIP_MEMORY_SCOPE_AGENT);
    }
    // no trailing barrier: next-iter LDS writes to hs_[u] are gated on unit-u
    // tags, published only after the owning lane consumed hs_[u].
  }
}

// ---------------- heads: oq, v_gain, u_gain, ff(cumsum), fb ----------------
__global__ __launch_bounds__(256) void k_heads(
    const float* __restrict__ hs,
    const float* __restrict__ Woq, const float* __restrict__ boq,
    const float* __restrict__ Wvg, const float* __restrict__ bvg,
    const float* __restrict__ Wug, const float* __restrict__ bug,
    const float* __restrict__ Wff, const float* __restrict__ bff,
    const float* __restrict__ Wfb, const float* __restrict__ bfb,
    float* __restrict__ out,
    float* __restrict__ oqw, float* __restrict__ vgw, float* __restrict__ ugw,
    float* __restrict__ ffw, float* __restrict__ fbw)
{
  int bf = blockIdx.x, tid = threadIdx.x;
  const float* h = hs + (size_t)bf * 512;
  float p[11];
  #pragma unroll
  for (int i = 0; i < 11; ++i) p[i] = 0.f;
  for (int k = tid; k < 512; k += 256) {
    float hv = h[k];
    p[0] = fmaf(Woq[k], hv, p[0]);
    p[1] = fmaf(Wvg[k], hv, p[1]);
    p[2] = fmaf(Wug[k], hv, p[2]);
    p[3] = fmaf(Wff[k], hv, p[3]);
    p[4] = fmaf(Wff[512 + k], hv, p[4]);
    p[5] = fmaf(Wff[1024 + k], hv, p[5]);
    p[6] = fmaf(Wff[1536 + k], hv, p[6]);
    p[7] = fmaf(Wfb[k], hv, p[7]);
    p[8] = fmaf(Wfb[512 + k], hv, p[8]);
    p[9] = fmaf(Wfb[1024 + k], hv, p[9]);
    p[10] = fmaf(Wfb[1536 + k], hv, p[10]);
  }
  #pragma unroll
  for (int i = 0; i < 11; ++i) {
    float v = p[i];
    #pragma unroll
    for (int m = 1; m < 64; m <<= 1) v += __shfl_xor(v, m);
    p[i] = v;
  }
  __shared__ float r4[4][11];
  if ((tid & 63) == 0) {
    int w = tid >> 6;
    #pragma unroll
    for (int i = 0; i < 11; ++i) r4[w][i] = p[i];
  }
  __syncthreads();
  if (tid == 0) {
    float s[11];
    #pragma unroll
    for (int i = 0; i < 11; ++i) s[i] = r4[0][i] + r4[1][i] + r4[2][i] + r4[3][i];
    float oqv = sigmoidf_(s[0] + boq[0]);
    float vg = softplusf(s[1] + bvg[0]);
    float ug = softplusf(s[2] + bug[0]);
    out[O1 + bf] = oqv; oqw[bf] = oqv;
    out[O2 + bf] = vg;  vgw[bf] = vg;
    out[O3 + bf] = ug;  ugw[bf] = ug;
    float run = 200.0f;
    #pragma unroll
    for (int j = 0; j < 4; ++j) {
      run += softplusf(s[3 + j] + bff[j]);
      out[O4 + (size_t)bf * 4 + j] = run; ffw[(size_t)bf * 4 + j] = run;
    }
    #pragma unroll
    for (int j = 0; j < 4; ++j) {
      float g = softplusf(s[7 + j] + bfb[j]) + 50.0f;
      out[O5 + (size_t)bf * 4 + j] = g; fbw[(size_t)bf * 4 + j] = g;
    }
  }
}

// ---------------- per-batch prefix scan of cycles -> start phase ----------------
__global__ __launch_bounds__(256) void k_scan(const float* __restrict__ f0, float* __restrict__ startw) {
  __shared__ float ts[256];
  int b = blockIdx.x, tid = threadIdx.x;
  const float CY = 256.0f / 24000.0f;
  float c[8], run = 0.f;
  int base = b * 2048 + tid * 8;
  #pragma unroll
  for (int j = 0; j < 8; ++j) { c[j] = run; run += f0[base + j] * CY; }
  ts[tid] = run;
  __syncthreads();
  for (int off = 1; off < 256; off <<= 1) {
    float v = (tid >= off) ? ts[tid - off] : 0.0f;
    __syncthreads();
    ts[tid] += v;
    __syncthreads();
  }
  float excl = (tid == 0) ? 0.0f : ts[tid - 1];
  #pragma unroll
  for (int j = 0; j < 8; ++j) {
    float st = excl + c[j];
    startw[base + j] = st - floorf(st);
  }
}

// ---------------- glottal source + excitation ----------------
__global__ __launch_bounds__(256) void k_excite(
    const float* __restrict__ f0, const float* __restrict__ noise,
    const float* __restrict__ startw, const float* __restrict__ oqw,
    const float* __restrict__ vgw, const float* __restrict__ ugw,
    float* __restrict__ exc)
{
  int bf = blockIdx.x, i = threadIdx.x;
  float st = startw[bf], f0v = f0[bf], oqv = oqw[bf], vg = vgw[bf], ug = ugw[bf];
  float total = st + f0v * ((float)i * (1.0f / 24000.0f));
  float phi = total - floorf(total);
  float peak = oqv * 0.66f;
  float rise = 0.5f * (1.0f - cosf(PI_F * phi / (peak + 1e-6f)));
  float fall = cosf(PI_F * (phi - peak) / (2.0f * (oqv - peak) + 1e-6f));
  float v = (phi < peak) ? rise : ((phi < oqv) ? fall : 0.0f);
  exc[(size_t)bf * 256 + i] = v * vg + noise[(size_t)bf * 256 + i] * ug;
}

// ---------------- formant IR generation + normalization (stored reversed) ----------------
__global__ __launch_bounds__(256) void k_ir(
    const float* __restrict__ ffw, const float* __restrict__ fbw,
    float* __restrict__ filtR)
{
  __shared__ float ffs[4], fbs[4], ssc[1], wmax[4];
  int bf = blockIdx.x, tid = threadIdx.x;
  if (tid < 4) { ffs[tid] = ffw[(size_t)bf * 4 + tid]; fbs[tid] = fbw[(size_t)bf * 4 + tid]; }
  __syncthreads();
  float vals[4];
  float am = 0.f;
  #pragma unroll
  for (int it = 0; it < 4; ++it) {
    int k = it * 256 + tid;
    float t = (float)k * (1.0f / 24000.0f);
    float s = 0.f;
    #pragma unroll
    for (int j = 0; j < 4; ++j)
      s += expf(-PI_F * fbs[j] * t) * sinf(TWO_PI_F * ffs[j] * t);
    vals[it] = s;
    am = fmaxf(am, fabsf(s));
  }
  #pragma unroll
  for (int m = 1; m < 64; m <<= 1) am = fmaxf(am, __shfl_xor(am, m));
  if ((tid & 63) == 0) wmax[tid >> 6] = am;
  __syncthreads();
  if (tid == 0) ssc[0] = fmaxf(fmaxf(wmax[0], wmax[1]), fmaxf(wmax[2], wmax[3])) + 1e-8f;
  __syncthreads();
  float inv = 1.0f / ssc[0];
  #pragma unroll
  for (int it = 0; it < 4; ++it) {
    int k = it * 256 + tid;
    filtR[(size_t)bf * 1024 + (1023 - k)] = vals[it] * inv;
  }
}

// ---------------- per-frame FIR conv (full) + overlap-add via atomics ----------------
__global__ __launch_bounds__(256) void k_conv(
    const float* __restrict__ exc, const float* __restrict__ filtR,
    float* __restrict__ audio)
{
  __shared__ float es[256];
  __shared__ float fp[1536];
  int bf = blockIdx.x, tid = threadIdx.x;
  int b = bf >> 11, f = bf & 2047;
  es[tid] = exc[(size_t)bf * 256 + tid];
  for (int i = tid; i < 1536; i += 256) {
    int j = i - 256;
    fp[i] = (j >= 0 && j < 1024) ? filtR[(size_t)bf * 1024 + j] : 0.0f;
  }
  __syncthreads();
  int n0 = tid * 5;
  float V0 = fp[n0 + 256], V1 = fp[n0 + 257], V2 = fp[n0 + 258], V3 = fp[n0 + 259], V4 = fp[n0 + 260];
  float a0 = 0.f, a1 = 0.f, a2 = 0.f, a3 = 0.f, a4 = 0.f;
  #pragma unroll 4
  for (int m = 0; m < 256; ++m) {
    float e = es[m];
    a0 = fmaf(e, V0, a0); a1 = fmaf(e, V1, a1); a2 = fmaf(e, V2, a2);
    a3 = fmaf(e, V3, a3); a4 = fmaf(e, V4, a4);
    V4 = V3; V3 = V2; V2 = V1; V1 = V0;
    V0 = fp[n0 + 255 - m];
  }
  float* arow = audio + (size_t)b * AROW + APAD + (size_t)f * 256;
  if (n0 + 0 < LL) atomicAdd(&arow[n0 + 0], a0);
  if (n0 + 1 < LL) atomicAdd(&arow[n0 + 1], a1);
  if (n0 + 2 < LL) atomicAdd(&arow[n0 + 2], a2);
  if (n0 + 3 < LL) atomicAdd(&arow[n0 + 3], a3);
  if (n0 + 4 < LL) atomicAdd(&arow[n0 + 4], a4);
}

// ---------------- pad reverb ir to 24064 with zeros ----------------
__global__ __launch_bounds__(256) void k_padir(const float* __restrict__ ir, float* __restrict__ irp) {
  int i = blockIdx.x * 256 + threadIdx.x;
  if (i < 24064) irp[i] = (i < REV) ? ir[i] : 0.0f;
}

// ---------------- reverb FIR (24000 taps) + wet/dry mix ----------------
// ir taps read via wave-uniform global loads (scalarize to s_load + v_fma w/ sgpr)
__global__ __launch_bounds__(256) void k_reverb(
    const float* __restrict__ audio, const float* __restrict__ irp,
    const float* __restrict__ wetl, float* __restrict__ out)
{
  __shared__ float as_[2376];   // 2304 window + swizzle pad
  int tb = blockIdx.x, b = blockIdx.y, tid = threadIdx.x;
  int tbase = tb * 2048;
  const float* arow = audio + (size_t)b * AROW;
  float acc[8];
  #pragma unroll
  for (int j = 0; j < 8; ++j) acc[j] = 0.f;

  for (int c = 0; c < 94; ++c) {
    __syncthreads();
    int B0 = APAD + tbase - c * 256 - 256;   // >= 0 always
    for (int i = tid; i < 2304; i += 256) {
      int g = B0 + i;
      float v = (g < (int)AROW) ? arow[g] : 0.0f;
      as_[i + (i >> 5)] = v;
    }
    __syncthreads();
    const float* irc = irp + c * 256;        // uniform -> scalar loads
    int base = 8 * tid + 256;
    int li;
    li = base + 0; float V0 = as_[li + (li >> 5)];
    li = base + 1; float V1 = as_[li + (li >> 5)];
    li = base + 2; float V2 = as_[li + (li >> 5)];
    li = base + 3; float V3 = as_[li + (li >> 5)];
    li = base + 4; float V4 = as_[li + (li >> 5)];
    li = base + 5; float V5 = as_[li + (li >> 5)];
    li = base + 6; float V6 = as_[li + (li >> 5)];
    li = base + 7; float V7 = as_[li + (li >> 5)];
    #pragma unroll 16
    for (int rr = 0; rr < 256; ++rr) {
      float w = irc[rr];
      acc[0] = fmaf(w, V0, acc[0]); acc[1] = fmaf(w, V1, acc[1]);
      acc[2] = fmaf(w, V2, acc[2]); acc[3] = fmaf(w, V3, acc[3]);
      acc[4] = fmaf(w, V4, acc[4]); acc[5] = fmaf(w, V5, acc[5]);
      acc[6] = fmaf(w, V6, acc[6]); acc[7] = fmaf(w, V7, acc[7]);
      V7 = V6; V6 = V5; V5 = V4; V4 = V3; V3 = V2; V2 = V1; V1 = V0;
      int ln = base - 1 - rr;
      V0 = as_[ln + (ln >> 5)];
    }
  }
  float wet = sigmoidf_(wetl[0]);
  #pragma unroll
  for (int j = 0; j < 8; ++j) {
    long t = (long)tbase + 8 * tid + j;
    if (t < (long)TOT) {
      float av = arow[APAD + t];
      out[(size_t)b * TOT + t] = (1.0f - wet) * av + wet * acc[j];
    }
  }
}

// ---------------- launch ----------------
extern "C" void kernel_launch(void* const* d_in, const int* in_sizes, int n_in,
                              void* d_out, int out_size, void* d_ws, size_t ws_size,
                              hipStream_t stream) {
  const float* f0       = (const float*)d_in[0];
  const float* loud     = (const float*)d_in[1];
  const float* gender   = (const float*)d_in[2];
  const float* age      = (const float*)d_in[3];
  const float* z        = (const float*)d_in[4];
  const float* noise    = (const float*)d_in[5];
  const float* W_in     = (const float*)d_in[6];
  const float* b_in     = (const float*)d_in[7];
  const float* W_ih     = (const float*)d_in[8];
  const float* W_hh     = (const float*)d_in[9];
  const float* b_ih     = (const float*)d_in[10];
  const float* b_hh     = (const float*)d_in[11];
  const float* W_oq     = (const float*)d_in[12];
  const float* b_oq     = (const float*)d_in[13];
  const float* W_vg     = (const float*)d_in[14];
  const float* b_vg     = (const float*)d_in[15];
  const float* W_ug     = (const float*)d_in[16];
  const float* b_ug     = (const float*)d_in[17];
  const float* W_ff     = (const float*)d_in[18];
  const float* b_ff     = (const float*)d_in[19];
  const float* W_fb     = (const float*)d_in[20];
  const float* b_fb     = (const float*)d_in[21];
  const float* rev_ir   = (const float*)d_in[22];
  const float* wet_l    = (const float*)d_in[23];

  float* out = (float*)d_out;
  char* ws = (char*)d_ws;
  float* x      = (float*)(ws + OFF_X);
  float* gi     = (float*)(ws + OFF_GI);
  float* hs     = (float*)(ws + OFF_HS);
  float* filtR  = (float*)(ws + OFF_FILTR);
  float* oqw    = (float*)(ws + OFF_OQ);
  float* vgw    = (float*)(ws + OFF_VG);
  float* ugw    = (float*)(ws + OFF_UG);
  float* ffw    = (float*)(ws + OFF_FFW);
  float* fbw    = (float*)(ws + OFF_FBW);
  float* startw = (float*)(ws + OFF_START);
  float* f0m    = (float*)(ws + OFF_F0M);
  unsigned long long* hbuf = (unsigned long long*)(ws + OFF_HBUF);
  float* exc    = (float*)(ws + OFF_EXC);
  float* irp    = (float*)(ws + OFF_IRP);
  float* audio  = (float*)(ws + OFF_AUDIO);

  // zero tagged h double-buffer (32KB, overlays ffw until k_heads) + audio acc
  hipMemsetAsync(ws + OFF_HBUF, 0, 32768, stream);
  hipMemsetAsync(ws + OFF_AUDIO, 0, (size_t)4 * AROW * 4, stream);

  k_f0mean<<<4, 256, 0, stream>>>(f0, f0m);
  k_inproj<<<512, 256, 0, stream>>>(f0, loud, gender, age, z, f0m, W_in, b_in, x);
  k_gemm_gi<<<dim3(24, 128), 256, 0, stream>>>(x, W_ih, b_ih, gi);
  k_gru<<<64, 256, 0, stream>>>(W_hh, b_hh, gi, hs, hbuf);
  k_heads<<<8192, 256, 0, stream>>>(hs, W_oq, b_oq, W_vg, b_vg, W_ug, b_ug,
                                    W_ff, b_ff, W_fb, b_fb, out, oqw, vgw, ugw, ffw, fbw);
  k_scan<<<4, 256, 0, stream>>>(f0, startw);
  k_excite<<<8192, 256, 0, stream>>>(f0, noise, startw, oqw, vgw, ugw, exc);
  k_ir<<<8192, 256, 0, stream>>>(ffw, fbw, filtR);
  k_conv<<<8192, 256, 0, stream>>>(exc, filtR, audio);
  k_padir<<<94, 256, 0, stream>>>(rev_ir, irp);   // gi region dead after k_gru
  k_reverb<<<dim3(257, 4), 256, 0, stream>>>(audio, irp, wet_l, out);
}